// Round 2
// baseline (111.944 us; speedup 1.0000x reference)
//
#include <hip/hip_runtime.h>
#include <hip/hip_bf16.h>

// Problem constants
#define B_   8
#define CIN  128
#define CKEY 256   // N_HEADS*HEAD_DIM key channels
#define NH   8
#define HOUT 32    // OUT_CH / N_HEADS
#define CPH  288   // softmax length per head
#define HW   4096

// E global scratch: exp(key_map) with borders, [b][row 0..65][px 0..65][ch 0..255] bf16
// borders (row 0, row 65, px 0, px 65) hold 1.0 = exp(0), matching ZeroPad2d.
#define EPX   256                       // elems per px (ch)
#define EROWG (66 * EPX)                // 16896 elems per row
#define EBATG (66 * EROWG)              // 1,115,136 elems per b
#define E_BYTES   ((size_t)B_ * EBATG * 2)   // 17,842,176 B
#define MFRAG_OFF E_BYTES                    // 16B-aligned

typedef __attribute__((ext_vector_type(8))) short bf16x8;
typedef __attribute__((ext_vector_type(4))) float f32x4;

static __device__ __forceinline__ unsigned bfpack2(float a, float b) {  // RNE pair
  __hip_bfloat162 h = __float22bfloat162_rn(float2{a, b});
  unsigned r;
  __builtin_memcpy(&r, &h, 4);
  return r;
}
static __device__ __forceinline__ unsigned short f2bf(float f) {
  unsigned u = __builtin_bit_cast(unsigned, f);
  u += 0x7FFFu + ((u >> 16) & 1u);
  return (unsigned short)(u >> 16);
}

// ---------------------------------------------------------------------------
// conv_kernel: blocks 0..511 = (b = bid&7, y = bid>>3). 1x1 conv (GEMM) row +
// exp -> E global (bf16) + 1.0 borders. 17 KB LDS, ~100 VGPR -> 2 blocks/CU.
// Blocks 512..529: pack memory B-frags into workspace (round-0 prep layout):
// c = ((m-p)&7)+8s, t = (9c+p)>>3; n-idx li -> i = ib*16+li, k = q*8+j -> s.
// ---------------------------------------------------------------------------
__global__ __launch_bounds__(512, 2) void conv_kernel(
    const float* __restrict__ x, const float* __restrict__ wk,
    const float* __restrict__ bk, const float* __restrict__ mem,
    unsigned short* __restrict__ EG, unsigned short* __restrict__ mfragP)
{
  __shared__ unsigned xdw[64 * 68];     // swizzled x row, 68 dw/px
  const int tid = threadIdx.x;
  const int gb = blockIdx.x;

  if (gb >= 512) {                      // ---- mfrag prep (18 blocks) ----
    const int idx  = (gb - 512) * 512 + tid;   // 0..9215
    const int lane = idx & 63, fi = idx >> 6;  // fi 0..143
    const int ib = fi & 1, pm = fi >> 1;
    const int p = pm % 9, mh = pm / 9;
    const int li = lane & 15, q = lane >> 4;
    const int i = ib * 16 + li;
    unsigned short* dst = mfragP + (size_t)idx * 8;
#pragma unroll
    for (int j = 0; j < 8; ++j) {
      const int s = q * 8 + j;
      const int c = ((mh - p + 8) & 7) + 8 * s;
      const int t = (9 * c + p) >> 3;
      dst[j] = f2bf(mem[((size_t)mh * CPH + t) * HOUT + i]);
    }
    return;
  }

  const int b = gb & 7;                 // batch per XCD (matches attn swizzle)
  const int y = gb >> 3;                // 0..63
  const int lane = tid & 63;
  const int wv = __builtin_amdgcn_readfirstlane(tid >> 6);
  const int li = lane & 15, q = lane >> 4;
  const int spx = tid & 63, sicg = tid >> 6;
  const int sxor = ((spx >> 3) & 7) << 3;   // 16B-block bank swizzle

  // bias, permuted: tile (cm=wv, sh), row r -> och = wv + 8*(sh*16+4q+r)
  float bias[2][4];
#pragma unroll
  for (int sh = 0; sh < 2; ++sh)
#pragma unroll
    for (int r = 0; r < 4; ++r)
      bias[sh][r] = bk[wv + 8 * (sh * 16 + 4 * q + r)];

  // x row load (exact, no halo: conv is 1x1) — 256B coalesced per instr
  unsigned pk[8];
  const float* xr = x + (size_t)b * CIN * HW + y * 64 + spx;
#pragma unroll
  for (int r4 = 0; r4 < 4; ++r4) {
    const int ic0 = 4 * sicg + 32 * r4;
    const float v0 = xr[(size_t)(ic0 + 0) * HW];
    const float v1 = xr[(size_t)(ic0 + 1) * HW];
    const float v2 = xr[(size_t)(ic0 + 2) * HW];
    const float v3 = xr[(size_t)(ic0 + 3) * HW];
    pk[2 * r4 + 0] = bfpack2(v0, v1);
    pk[2 * r4 + 1] = bfpack2(v2, v3);
  }

  // per-wave W A-frags from wk (och = wv + 8*(sh*16+li), ic = ks*32+q*8+j)
  bf16x8 wf[2][4];
#pragma unroll
  for (int sh = 0; sh < 2; ++sh)
#pragma unroll
    for (int ks = 0; ks < 4; ++ks) {
      const int och = wv + 8 * (sh * 16 + li);
      const float* src = wk + (size_t)och * CIN + ks * 32 + q * 8;
      const float4 v0 = *(const float4*)(src);
      const float4 v1 = *(const float4*)(src + 4);
      const int4 piv = make_int4(bfpack2(v0.x, v0.y), bfpack2(v0.z, v0.w),
                                 bfpack2(v1.x, v1.y), bfpack2(v1.z, v1.w));
      wf[sh][ks] = __builtin_bit_cast(bf16x8, piv);
    }

  // stage x row into LDS (swizzled)
#pragma unroll
  for (int r4 = 0; r4 < 4; ++r4) {
    const int o = (2 * sicg + 16 * r4) ^ sxor;
    *(uint2*)(xdw + spx * 68 + o) = make_uint2(pk[2 * r4], pk[2 * r4 + 1]);
  }
  __syncthreads();

  // GEMM: 256 och x 128 ic x 64 px
  f32x4 acc[2][4];                      // [sh][pt]
#pragma unroll
  for (int sh = 0; sh < 2; ++sh)
#pragma unroll
    for (int pt = 0; pt < 4; ++pt) {
      f32x4 cv; cv[0] = bias[sh][0]; cv[1] = bias[sh][1];
      cv[2] = bias[sh][2]; cv[3] = bias[sh][3];
      acc[sh][pt] = cv;
    }
#pragma unroll
  for (int ks = 0; ks < 4; ++ks) {
    const bf16x8 a0 = wf[0][ks];
    const bf16x8 a1 = wf[1][ks];
#pragma unroll
    for (int pt = 0; pt < 4; ++pt) {
      const int px  = pt * 16 + li;
      const int blk = (ks * 16 + q * 4) ^ (((px >> 3) & 7) << 3);
      const bf16x8 bfr = *(const bf16x8*)(xdw + px * 68 + blk);
      acc[0][pt] = __builtin_amdgcn_mfma_f32_16x16x32_bf16(a0, bfr, acc[0][pt], 0, 0, 0);
      acc[1][pt] = __builtin_amdgcn_mfma_f32_16x16x32_bf16(a1, bfr, acc[1][pt], 0, 0, 0);
    }
  }

  // exp + E global write: lane's 4 s-values contiguous -> 8B stores
  unsigned short* erow = EG + (size_t)(b * 66 + y + 1) * EROWG;
#pragma unroll
  for (int sh = 0; sh < 2; ++sh)
#pragma unroll
    for (int pt = 0; pt < 4; ++pt) {
      const float w0 = __expf(acc[sh][pt][0]);
      const float w1 = __expf(acc[sh][pt][1]);
      const float w2 = __expf(acc[sh][pt][2]);
      const float w3 = __expf(acc[sh][pt][3]);
      unsigned short* dst = erow + (size_t)(pt * 16 + li + 1) * EPX
                          + wv * 32 + sh * 16 + 4 * q;
      *(uint2*)dst = make_uint2(bfpack2(w0, w1), bfpack2(w2, w3));
    }

  // borders = exp(0) = 1.0
  unsigned* rowdw = (unsigned*)erow;    // this row: px 0 and px 65
  if (tid < 256) {
    const int c = tid & 127;
    if (tid < 128) rowdw[c] = 0x3F803F80u;
    else           rowdw[65 * 128 + c] = 0x3F803F80u;
  }
  if (y == 0) {                         // top border row
    unsigned* r0 = (unsigned*)(EG + (size_t)(b * 66 + 0) * EROWG);
    for (int d = tid; d < 66 * 128; d += 512) r0[d] = 0x3F803F80u;
  }
  if (y == 63) {                        // bottom border row
    unsigned* r65 = (unsigned*)(EG + (size_t)(b * 66 + 65) * EROWG);
    for (int d = tid; d < 66 * 128; d += 512) r65[d] = 0x3F803F80u;
  }
}

// ---------------------------------------------------------------------------
// attn_kernel: grid 512 = (b = bid&7, h = bid>>3); 512 threads, wave = head m.
// No LDS; E fragments read straight from global (L2-hot, same XCD as writer).
// Swapped-operand MFMA: A = memory frag (row=i), B = attn frag (col=px)
// -> D[i][px] stores coalesce directly; denominator = mfma(ones, attn).
// ---------------------------------------------------------------------------
__global__ __launch_bounds__(512, 2) void attn_kernel(
    const unsigned short* __restrict__ EG,
    const unsigned short* __restrict__ mfragP,
    float* __restrict__ out)
{
  const int tid = threadIdx.x, bid = blockIdx.x;
  const int b = bid & 7, h = bid >> 3;
  const int lane = tid & 63;
  const int m = __builtin_amdgcn_readfirstlane(tid >> 6);
  const int li = lane & 15, q = lane >> 4;

  const unsigned short* mf = mfragP + (size_t)(m * 9) * 2 * 64 * 8;
  const int4 onesi = make_int4(0x3F803F80, 0x3F803F80, 0x3F803F80, 0x3F803F80);
  const bf16x8 bones = __builtin_bit_cast(bf16x8, onesi);

  f32x4 acc[4][2], accs[4];
#pragma unroll
  for (int pb = 0; pb < 4; ++pb) {
    acc[pb][0] = {0.f, 0.f, 0.f, 0.f};
    acc[pb][1] = {0.f, 0.f, 0.f, 0.f};
    accs[pb]   = {0.f, 0.f, 0.f, 0.f};
  }

#pragma unroll
  for (int p = 0; p < 9; ++p) {
    const bf16x8 bm0 = *(const bf16x8*)(mf + ((size_t)((p * 2 + 0) * 64 + lane)) * 8);
    const bf16x8 bm1 = *(const bf16x8*)(mf + ((size_t)((p * 2 + 1) * 64 + lane)) * 8);
    const int cm  = (m - p + 8) & 7;
    const int ry  = h + p / 3;          // padded row index 0..65
    const int dxp = p - 3 * (p / 3);
    const unsigned short* abase = EG + (size_t)(b * 66 + ry) * EROWG
                                + (size_t)(li + dxp) * EPX + cm * 32 + q * 8;
#pragma unroll
    for (int pb = 0; pb < 4; ++pb) {
      const bf16x8 af = *(const bf16x8*)(abase + (size_t)pb * 16 * EPX);  // 16B
      acc[pb][0] = __builtin_amdgcn_mfma_f32_16x16x32_bf16(bm0, af, acc[pb][0], 0, 0, 0);
      acc[pb][1] = __builtin_amdgcn_mfma_f32_16x16x32_bf16(bm1, af, acc[pb][1], 0, 0, 0);
      accs[pb]   = __builtin_amdgcn_mfma_f32_16x16x32_bf16(bones, af, accs[pb], 0, 0, 0);
    }
  }

  float* ob = out + ((size_t)(b * CKEY + m * HOUT)) * HW + h * 64;
#pragma unroll
  for (int pb = 0; pb < 4; ++pb) {
    // A = ones makes every accs row the per-pixel denominator (px = li)
    const float inv = 1.0f / accs[pb][0];
#pragma unroll
    for (int n = 0; n < 2; ++n)
#pragma unroll
      for (int r = 0; r < 4; ++r)
        ob[(size_t)(n * 16 + 4 * q + r) * HW + pb * 16 + li] =
            acc[pb][n][r] * inv;        // 4x64B segments per store instr
  }
}

extern "C" void kernel_launch(void* const* d_in, const int* in_sizes, int n_in,
                              void* d_out, int out_size, void* d_ws, size_t ws_size,
                              hipStream_t stream) {
  const float* x   = (const float*)d_in[0];
  const float* wk  = (const float*)d_in[1];
  const float* bk  = (const float*)d_in[2];
  const float* mem = (const float*)d_in[3];

  unsigned short* EG     = (unsigned short*)d_ws;
  unsigned short* mfragP = (unsigned short*)((char*)d_ws + MFRAG_OFF);

  conv_kernel<<<dim3(530), dim3(512), 0, stream>>>(x, wk, bk, mem, EG, mfragP);
  attn_kernel<<<dim3(512), dim3(512), 0, stream>>>(EG, mfragP, (float*)d_out);
}

// Round 3
// 94.527 us; speedup vs baseline: 1.1843x; 1.1843x over previous
//
#include <hip/hip_runtime.h>
#include <hip/hip_bf16.h>

// Problem constants
#define B_   8
#define CIN  128
#define CKEY 256   // N_HEADS*HEAD_DIM key channels
#define NH   8
#define HOUT 32    // OUT_CH / N_HEADS
#define CPH  288   // softmax length per head
#define HW   4096

// LDS geometry (identical to the proven r0 layout)
#define ESTR   264                 // E2 x-stride in bf16 (132 dw; 16B-aligned blocks)
#define EROW   (66 * ESTR)         // 17424 elems per y-row
#define E2_BYTES   (4 * EROW * 2)            // 139392 (rows h0-1..h0+2)
#define XBUF_BYTES (64 * 136 * 2)            // 17408 (68 dw per px, swizzled)
#define SMEM_BYTES (E2_BYTES + XBUF_BYTES)   // 156800 <= 160 KiB

typedef __attribute__((ext_vector_type(8))) short bf16x8;
typedef __attribute__((ext_vector_type(4))) float f32x4;

static __device__ __forceinline__ unsigned bfpack2(float a, float b) {  // RNE pair
  __hip_bfloat162 h = __float22bfloat162_rn(float2{a, b});
  unsigned r;
  __builtin_memcpy(&r, &h, 4);
  return r;
}
static __device__ __forceinline__ unsigned short f2bf(float f) {
  unsigned u = __builtin_bit_cast(unsigned, f);
  u += 0x7FFFu + ((u >> 16) & 1u);
  return (unsigned short)(u >> 16);
}

// ---------------------------------------------------------------------------
// prep_kernel: 36 blocks x 256 thr. Pack memory B-frags (reindexed by m,p,s):
// c = ((m-p)&7)+8s, t = (9c+p)>>3; n-idx li -> i = ib*16+li, k = q*8+j -> s.
// (Kept as a tiny separate dispatch: register-resident gather in the fused
// kernel spilled in round 1; per-p L2 reloads are the proven pattern.)
// ---------------------------------------------------------------------------
__global__ __launch_bounds__(256) void prep_kernel(
    const float* __restrict__ mem, unsigned short* __restrict__ mfragP)
{
  const int idx  = blockIdx.x * 256 + threadIdx.x;  // 0..9215
  const int lane = idx & 63, fi = idx >> 6;         // fi 0..143
  const int ib = fi & 1, pm = fi >> 1;
  const int p = pm % 9, m = pm / 9;
  const int li = lane & 15, q = lane >> 4;
  const int i = ib * 16 + li;
  unsigned short* dst = mfragP + (size_t)idx * 8;
#pragma unroll
  for (int j = 0; j < 8; ++j) {
    const int s = q * 8 + j;
    const int c = ((m - p + 8) & 7) + 8 * s;
    const int t = (9 * c + p) >> 3;
    dst[j] = f2bf(mem[((size_t)m * CPH + t) * HOUT + i]);
  }
}

// ---------------------------------------------------------------------------
// Fused conv + softmax + matvec, h-PAIR per block, 16 waves (1024 threads).
// grid = 256 (b = bid&7 XCD swizzle, hp = bid>>3, h0 = 2*hp) = 1 block/CU,
// 16 waves = 4 waves/SIMD (2x the previous occupancy).
// Phases:
//  0) issue ALL x global loads (4 rows h0-1..h0+2, packed bf16 in VGPRs);
//     in-kernel wf gather (16 VGPR, L2-hot wk)
//  1) per row: ds_write xbuf -> sync -> conv MFMA + exp -> E2 row -> sync
//     conv wave = (cm = wv&7, sh = wv>>3): 16 MFMA/wave (half of before)
//  2) attention: wave = (m = wv&7, hh = wv>>3) -- both h's in parallel.
//     per (p,pb): one ds_read_b128 A-frag from E2; SWAPPED-operand MFMA:
//     mfma(mem, attn) -> D[i][px]; denominator mfma(ones, attn)
//  3) epilogue: scale by 1/denom, store straight from acc (64B segments)
// ---------------------------------------------------------------------------
__global__ __launch_bounds__(1024) void fused_kernel(
    const float* __restrict__ x, const float* __restrict__ wk,
    const unsigned short* __restrict__ mfragP, const float* __restrict__ bk,
    float* __restrict__ out)
{
  extern __shared__ char smem[];
  unsigned short* e2 = (unsigned short*)smem;
  unsigned*       xdw = (unsigned*)(smem + E2_BYTES);       // xbuf, 68 dw/px

  const int tid = threadIdx.x;
  const int bid = blockIdx.x;
  const int b  = bid & 7;                   // XCD swizzle: batch per XCD
  const int h0 = (bid >> 3) * 2;
  const int lane = tid & 63;
  const int wv = __builtin_amdgcn_readfirstlane(tid >> 6);  // 0..15
  const int cm = wv & 7, sh = wv >> 3;
  const int li = lane & 15, q = lane >> 4;

  // ---- bias for conv wave (cm,sh): row r -> och = cm + 8*(sh*16+4q+r)
  float bias[4];
#pragma unroll
  for (int r = 0; r < 4; ++r)
    bias[r] = bk[cm + 8 * (sh * 16 + 4 * q + r)];

  // ================= phase 0: all x loads up-front =================
  const int spx = tid & 63, g = tid >> 6;   // g 0..15
  const int sxor = ((spx >> 3) & 7) << 3;   // 16B-block bank swizzle

  const bool valid[4] = {h0 - 1 >= 0, true, true, h0 + 2 < 64};
  unsigned pk[4][4];
#pragma unroll
  for (int r = 0; r < 4; ++r) {
    if (!valid[r]) continue;
    const int y = h0 - 1 + r;
    const float* xr = x + (size_t)b * CIN * HW + y * 64 + spx;
#pragma unroll
    for (int r2 = 0; r2 < 2; ++r2) {
      const int ic0 = 4 * g + 64 * r2;
      const float v0 = xr[(size_t)(ic0 + 0) * HW];   // 256B coalesced each
      const float v1 = xr[(size_t)(ic0 + 1) * HW];
      const float v2 = xr[(size_t)(ic0 + 2) * HW];
      const float v3 = xr[(size_t)(ic0 + 3) * HW];
      pk[r][2 * r2 + 0] = bfpack2(v0, v1);
      pk[r][2 * r2 + 1] = bfpack2(v2, v3);
    }
  }

  // ---- in-kernel W A-frags (och = cm + 8*(sh*16+li), ic = ks*32+q*8+j)
  bf16x8 wf[4];
#pragma unroll
  for (int ks = 0; ks < 4; ++ks) {
    const int och = cm + 8 * (sh * 16 + li);
    const float* src = wk + (size_t)och * CIN + ks * 32 + q * 8;
    const float4 v0 = *(const float4*)(src);
    const float4 v1 = *(const float4*)(src + 4);
    const int4 piv = make_int4(bfpack2(v0.x, v0.y), bfpack2(v0.z, v0.w),
                               bfpack2(v1.x, v1.y), bfpack2(v1.z, v1.w));
    wf[ks] = __builtin_bit_cast(bf16x8, piv);
  }

  // out-of-range rows -> exp(0) = 1.0 everywhere (before first sync)
#pragma unroll
  for (int r = 0; r < 4; r += 3) {
    if (!valid[r]) {
      unsigned* erow = (unsigned*)(e2 + r * EROW);
      for (int d = tid; d < 66 * 132; d += 1024) erow[d] = 0x3F803F80u;
    }
  }

  // ================= phase 1: conv rows =================
#pragma unroll
  for (int rr = 0; rr < 4; ++rr) {
    if (valid[rr]) {
#pragma unroll
      for (int r2 = 0; r2 < 2; ++r2) {
        const int o = (2 * g + 32 * r2) ^ sxor;
        *(uint2*)(xdw + spx * 68 + o) = make_uint2(pk[rr][2 * r2], pk[rr][2 * r2 + 1]);
      }
    }
    __syncthreads();
    if (valid[rr]) {
      f32x4 acc[4];                         // [pt], wave owns (cm,sh)
#pragma unroll
      for (int pt = 0; pt < 4; ++pt) {
        f32x4 cv; cv[0] = bias[0]; cv[1] = bias[1];
        cv[2] = bias[2]; cv[3] = bias[3];
        acc[pt] = cv;
      }
#pragma unroll
      for (int ks = 0; ks < 4; ++ks) {
        const bf16x8 a0 = wf[ks];
#pragma unroll
        for (int pt = 0; pt < 4; ++pt) {
          const int px  = pt * 16 + li;
          const int blk = (ks * 16 + q * 4) ^ (((px >> 3) & 7) << 3);
          const bf16x8 bfr = *(const bf16x8*)(xdw + px * 68 + blk);
          acc[pt] = __builtin_amdgcn_mfma_f32_16x16x32_bf16(a0, bfr, acc[pt], 0, 0, 0);
        }
      }
      // exp + E2 write: lane's 4 s-values contiguous -> b64
      unsigned short* erow = e2 + rr * EROW;
#pragma unroll
      for (int pt = 0; pt < 4; ++pt) {
        const float w0 = __expf(acc[pt][0]);
        const float w1 = __expf(acc[pt][1]);
        const float w2 = __expf(acc[pt][2]);
        const float w3 = __expf(acc[pt][3]);
        unsigned short* dst = erow + (pt * 16 + li + 1) * ESTR
                            + cm * 32 + sh * 16 + 4 * q;
        *(uint2*)dst = make_uint2(bfpack2(w0, w1), bfpack2(w2, w3));
      }
      if (tid < 256) {                      // x-borders = exp(0) = 1.0
        const int xcol = (tid & 1) ? 65 : 0;
        ((unsigned*)(erow + xcol * ESTR))[tid >> 1] = 0x3F803F80u;
      }
    }
    __syncthreads();
  }

  // ================= phase 2+3: attention, wave = (m, hh) =================
  const int m = cm, hh = sh;
  const unsigned short* mf = mfragP + (size_t)(m * 9) * 2 * 64 * 8;
  const int4 onesi = make_int4(0x3F803F80, 0x3F803F80, 0x3F803F80, 0x3F803F80);
  const bf16x8 bones = __builtin_bit_cast(bf16x8, onesi);

  f32x4 acc[4][2], accs[4];
#pragma unroll
  for (int pb = 0; pb < 4; ++pb) {
    acc[pb][0] = {0.f, 0.f, 0.f, 0.f};
    acc[pb][1] = {0.f, 0.f, 0.f, 0.f};
    accs[pb]   = {0.f, 0.f, 0.f, 0.f};
  }
#pragma unroll
  for (int p = 0; p < 9; ++p) {
    const bf16x8 bm0 = *(const bf16x8*)(mf + ((size_t)((p * 2 + 0) * 64 + lane)) * 8);
    const bf16x8 bm1 = *(const bf16x8*)(mf + ((size_t)((p * 2 + 1) * 64 + lane)) * 8);
    const int cmp  = (m - p + 8) & 7;
    const int rrow = hh + p / 3;
    const int dxp  = p - 3 * (p / 3);
    const unsigned short* abase = e2 + rrow * EROW + (li + dxp) * ESTR
                                + cmp * 32 + q * 8;
#pragma unroll
    for (int pb = 0; pb < 4; ++pb) {
      const bf16x8 af = *(const bf16x8*)(abase + pb * 16 * ESTR);  // b128
      // swapped operands: A = memory (row=i), B = attn (col=px)
      acc[pb][0] = __builtin_amdgcn_mfma_f32_16x16x32_bf16(bm0, af, acc[pb][0], 0, 0, 0);
      acc[pb][1] = __builtin_amdgcn_mfma_f32_16x16x32_bf16(bm1, af, acc[pb][1], 0, 0, 0);
      accs[pb]   = __builtin_amdgcn_mfma_f32_16x16x32_bf16(bones, af, accs[pb], 0, 0, 0);
    }
  }
  float* ob = out + ((size_t)(b * CKEY + m * HOUT)) * HW + (h0 + hh) * 64;
#pragma unroll
  for (int pb = 0; pb < 4; ++pb) {
    // A = ones makes every accs row the per-pixel denominator (px = li)
    const float inv = 1.0f / accs[pb][0];
#pragma unroll
    for (int n = 0; n < 2; ++n)
#pragma unroll
      for (int r = 0; r < 4; ++r)
        ob[(size_t)(n * 16 + 4 * q + r) * HW + pb * 16 + li] =
            acc[pb][n][r] * inv;            // 4x64B segments per store instr
  }
}

extern "C" void kernel_launch(void* const* d_in, const int* in_sizes, int n_in,
                              void* d_out, int out_size, void* d_ws, size_t ws_size,
                              hipStream_t stream) {
  const float* x   = (const float*)d_in[0];
  const float* wk  = (const float*)d_in[1];
  const float* bk  = (const float*)d_in[2];
  const float* mem = (const float*)d_in[3];

  unsigned short* mfragP = (unsigned short*)d_ws;   // 147,456 B

  (void)hipFuncSetAttribute((const void*)fused_kernel,
                            hipFuncAttributeMaxDynamicSharedMemorySize, SMEM_BYTES);

  prep_kernel<<<dim3(36), dim3(256), 0, stream>>>(mem, mfragP);
  fused_kernel<<<dim3(256), dim3(1024), SMEM_BYTES, stream>>>(
      x, wk, mfragP, bk, (float*)d_out);
}